// Round 3
// baseline (384.411 us; speedup 1.0000x reference)
//
#include <hip/hip_runtime.h>
#include <hip/hip_bf16.h>
#include <math.h>

#define DIMC   256
#define LSP    4096
#define BATCH  8
#define DINNER 512
#define NHEADS 8
#define HEADDIM 64
#define DSTATE 64
#define CONVDIM 640
#define DPROJ  1160
#define MPAD   1280
#define CHUNK  256
#define NCHUNK 16
#define LOG2E  1.44269504088896f

typedef unsigned short u16;
typedef __attribute__((ext_vector_type(8))) unsigned short u16x8;
typedef __attribute__((ext_vector_type(8))) short s16x8;
typedef __attribute__((ext_vector_type(4))) float f32x4;

#define MFMA16(a,b,c) __builtin_amdgcn_mfma_f32_16x16x32_bf16((s16x8)(a),(s16x8)(b),(c),0,0,0)

__device__ __forceinline__ float bf2f(u16 u){ return __uint_as_float(((unsigned int)u)<<16); }
__device__ __forceinline__ u16 f2bf(float f){
  unsigned int x = __float_as_uint(f);
  unsigned int r = (x + 0x7fffu + ((x>>16)&1u)) >> 16;
  return (u16)r;
}
__device__ __forceinline__ float exp2g(float x){ return __builtin_amdgcn_exp2f(x); }
__device__ __forceinline__ float softplusf(float x){ return (x > 20.f) ? x : __logf(1.f + __expf(x)); }
__device__ __forceinline__ float siluf(float x){ return x * __builtin_amdgcn_rcpf(1.f + __expf(-x)); }

// ---------------- weight fp32 -> bf16 (with trailing-row zero pad) ----------------
__global__ void convert_w(const float* __restrict__ src, u16* __restrict__ dst,
                          int total, int valid){
  int i = blockIdx.x*256 + threadIdx.x;
  if (i >= total) return;
  dst[i] = (i < valid) ? f2bf(src[i]) : (u16)0;
}

// ---------------- out_proj weight * rmsw fold -> bf16 ----------------
__global__ void convert_w_rms(const float* __restrict__ src, const float* __restrict__ rmsw,
                              u16* __restrict__ dst){
  int i = blockIdx.x*256 + threadIdx.x;
  if (i >= DIMC*DINNER) return;
  dst[i] = f2bf(src[i] * rmsw[i & (DINNER-1)]);
}

// ---------------- LayerNorm: x [b][c][l] fp32 -> XNT [b][l][c] bf16 ----------------
__global__ void ln_kernel(const float* __restrict__ X, const float* __restrict__ lnw,
                          const float* __restrict__ lnb, u16* __restrict__ XNT) {
  int pos = blockIdx.x*256 + threadIdx.x;
  int b = pos >> 12, l = pos & (LSP-1);
  const float* xb = X + ((size_t)b*DIMC)*LSP + l;
  float sum=0.f, sq=0.f;
  for (int c=0;c<DIMC;c++){ float v=xb[(size_t)c*LSP]; sum+=v; sq+=v*v; }
  float mu = sum*(1.f/DIMC);
  float var = sq*(1.f/DIMC) - mu*mu;
  float rs = rsqrtf(var + 1e-5f);
  u16* ob = XNT + ((size_t)(b*LSP + l))*DIMC;
  for (int c0=0;c0<DIMC;c0+=8){
    u16x8 v8;
    #pragma unroll
    for(int j=0;j<8;j++){
      float v = xb[(size_t)(c0+j)*LSP];
      v8[j] = f2bf((v-mu)*rs*lnw[c0+j] + lnb[c0+j]);
    }
    *(u16x8*)&ob[c0] = v8;
  }
}

// ---------------- Fused in_proj GEMM: XNT tile LDS-resident, loop over 5 proj tiles.
__global__ __launch_bounds__(256,2) void gemm_in_fused(
    const u16* __restrict__ W, const u16* __restrict__ XNT,
    u16* __restrict__ ZT, u16* __restrict__ XBC, u16* __restrict__ DT){
  __shared__ u16 Xs[128][264];
  __shared__ u16 Ws[128][32];
  int tid=threadIdx.x, w=tid>>6, lane=tid&63, l15=lane&15, quad=lane>>4;
  int n0=blockIdx.x*128, mh=blockIdx.y, b=blockIdx.z;
  {
    const u16* src = XNT + ((size_t)(b*LSP + n0))*DIMC;
    #pragma unroll
    for (int i=0;i<16;i++){
      int g = i*256 + tid;
      int row = g>>5, c8 = (g&31)*8;
      *(u16x8*)&Xs[row][c8] = *(const u16x8*)&src[(size_t)row*DIMC + c8];
    }
  }
  for (int pti=0; pti<5; pti++){
    int ptg = mh*5 + pti;
    int m0 = ptg*128;
    f32x4 acc[4][4];
    #pragma unroll
    for(int i=0;i<4;i++)
      #pragma unroll
      for(int j=0;j<4;j++) acc[i][j]=(f32x4){0.f,0.f,0.f,0.f};
    for (int k0=0;k0<DIMC;k0+=32){
      __syncthreads();
      {
        int ch = tid*2;
        int r = ch>>2, o=(ch&3)*8;
        *(u16x8*)&Ws[r][o] = *(const u16x8*)&W[(size_t)(m0+r)*DIMC + k0 + o];
        ch++; r = ch>>2; o=(ch&3)*8;
        *(u16x8*)&Ws[r][o] = *(const u16x8*)&W[(size_t)(m0+r)*DIMC + k0 + o];
      }
      __syncthreads();
      u16x8 af[4], bfr[4];
      if (ptg < 4){
        #pragma unroll
        for(int mt=0;mt<4;mt++) af[mt] = *(const u16x8*)&Xs[(w>>1)*64+mt*16+l15][k0+quad*8];
        #pragma unroll
        for(int nt=0;nt<4;nt++) bfr[nt] = *(const u16x8*)&Ws[(w&1)*64+nt*16+l15][quad*8];
      } else {
        #pragma unroll
        for(int mt=0;mt<4;mt++) af[mt] = *(const u16x8*)&Ws[(w>>1)*64+mt*16+l15][quad*8];
        #pragma unroll
        for(int nt=0;nt<4;nt++) bfr[nt] = *(const u16x8*)&Xs[(w&1)*64+nt*16+l15][k0+quad*8];
      }
      #pragma unroll
      for(int mt=0;mt<4;mt++)
        #pragma unroll
        for(int nt=0;nt<4;nt++)
          acc[mt][nt]=MFMA16(af[mt],bfr[nt],acc[mt][nt]);
    }
    if (ptg < 4){
      #pragma unroll
      for(int mt=0;mt<4;mt++)
        #pragma unroll
        for(int nt=0;nt<4;nt++)
          #pragma unroll
          for(int r=0;r<4;r++){
            int lrow = n0 + (w>>1)*64 + mt*16 + quad*4 + r;
            int dcol = m0 + (w&1)*64 + nt*16 + l15;
            ZT[((size_t)b*LSP + lrow)*DINNER + dcol] = f2bf(acc[mt][nt][r]);
          }
    } else {
      #pragma unroll
      for(int mt=0;mt<4;mt++)
        #pragma unroll
        for(int nt=0;nt<4;nt++)
          #pragma unroll
          for(int r=0;r<4;r++){
            int prow = m0 + (w>>1)*64 + mt*16 + quad*4 + r;
            if (prow>=DPROJ) continue;
            int col = n0 + (w&1)*64 + nt*16 + l15;
            u16 v = f2bf(acc[mt][nt][r]);
            if (prow<DINNER+CONVDIM)  XBC[((size_t)b*CONVDIM+(prow-DINNER))*LSP+col]=v;
            else                      DT[((size_t)b*NHEADS+(prow-DINNER-CONVDIM))*LSP+col]=v;
          }
    }
  }
}

// ---------------- GEMM2 (MFMA): W2' [256x512] x g [b,l,512]; rms folded into loader ---
__global__ void gemm_out_mfma(const u16* __restrict__ A, const u16* __restrict__ Bm,
                              const float* __restrict__ Res, float* __restrict__ Out){
  __shared__ u16 As[128][32];
  __shared__ u16 Bs[128][32];
  __shared__ float rinv[128];
  int tid=threadIdx.x, w=tid>>6, lane=tid&63, l15=lane&15, quad=lane>>4;
  int b=blockIdx.z, m0=blockIdx.y*128, n0=blockIdx.x*128;
  const u16* Bb = Bm + ((size_t)b*LSP + n0)*DINNER;
  f32x4 acc[4][4];
  #pragma unroll
  for(int i=0;i<4;i++)
    #pragma unroll
    for(int j=0;j<4;j++) acc[i][j] = (f32x4){0.f,0.f,0.f,0.f};
  float sqacc = 0.f;
  for (int k0=0;k0<DINNER;k0+=32){
    __syncthreads();
    {
      int ch = tid*2;
      int r = ch>>2, o=(ch&3)*8;
      *(u16x8*)&As[r][o] = *(const u16x8*)&A[(size_t)(m0+r)*DINNER + k0 + o];
      u16x8 bv = *(const u16x8*)&Bb[(size_t)r*DINNER + k0 + o];
      *(u16x8*)&Bs[r][o] = bv;
      #pragma unroll
      for(int j=0;j<8;j++){ float f=bf2f(bv[j]); sqacc += f*f; }
      ch++; r = ch>>2; o=(ch&3)*8;
      *(u16x8*)&As[r][o] = *(const u16x8*)&A[(size_t)(m0+r)*DINNER + k0 + o];
      u16x8 bv2 = *(const u16x8*)&Bb[(size_t)r*DINNER + k0 + o];
      *(u16x8*)&Bs[r][o] = bv2;
      #pragma unroll
      for(int j=0;j<8;j++){ float f=bf2f(bv2[j]); sqacc += f*f; }
    }
    __syncthreads();
    u16x8 af[4], bfr[4];
    #pragma unroll
    for(int mt=0;mt<4;mt++) af[mt] = *(const u16x8*)&As[(w>>1)*64+mt*16+l15][quad*8];
    #pragma unroll
    for(int nt=0;nt<4;nt++) bfr[nt] = *(const u16x8*)&Bs[(w&1)*64+nt*16+l15][quad*8];
    #pragma unroll
    for(int mt=0;mt<4;mt++)
      #pragma unroll
      for(int nt=0;nt<4;nt++)
        acc[mt][nt]=MFMA16(af[mt],bfr[nt],acc[mt][nt]);
  }
  // pair (tid, tid^1) covers one g-row; reduce and publish rinv
  {
    float tot = sqacc + __shfl_xor(sqacc, 1, 64);
    if ((tid&1)==0) rinv[tid>>1] = rsqrtf(tot*(1.f/DINNER) + 1e-5f);
  }
  __syncthreads();
  #pragma unroll
  for(int mt=0;mt<4;mt++)
    #pragma unroll
    for(int nt=0;nt<4;nt++){
      float rv = rinv[(w&1)*64 + nt*16 + l15];
      #pragma unroll
      for(int r=0;r<4;r++){
        int row = m0 + (w>>1)*64 + mt*16 + quad*4 + r;
        int col = n0 + (w&1)*64 + nt*16 + l15;
        size_t oi = ((size_t)b*DIMC+row)*LSP+col;
        Out[oi] = acc[mt][nt][r]*rv + Res[oi];
      }
    }
}

// ---------------- Depthwise 3x3 conv + bias + SiLU, IN-PLACE on XBC ----------------
__global__ void conv_kernel(u16* __restrict__ XBC, const float* __restrict__ CW,
                            const float* __restrict__ CB){
  int ch = blockIdx.x, b = blockIdx.y, tid = threadIdx.x;
  __shared__ float plane[66*66];
  u16* base = XBC + ((size_t)b*CONVDIM + ch)*LSP;
  for (int idx=tid; idx<66*66; idx+=256){
    int yy = idx/66 - 1, xx = idx%66 - 1;
    float v = 0.f;
    if (yy>=0 && yy<64 && xx>=0 && xx<64) v = bf2f(base[yy*64+xx]);
    plane[idx] = v;
  }
  float wg[9];
  #pragma unroll
  for (int t=0;t<9;t++) wg[t] = CW[ch*9+t];
  float bias = CB[ch];
  __syncthreads();
  for (int r=0;r<16;r++){
    int pix = tid + r*256;
    int y = pix>>6, x = pix&63;
    float s=0.f;
    #pragma unroll
    for(int dy=0;dy<3;dy++)
      #pragma unroll
      for(int dx=0;dx<3;dx++) s += plane[(y+dy)*66 + x+dx]*wg[dy*3+dx];
    base[pix] = f2bf(siluf(s + bias));
  }
}

// ---------------- SSD pre: dt softplus + per-chunk cumsum (LOG2E-scaled), ONCE ------
__global__ void ssd_pre_kernel(const u16* __restrict__ DT, const float* __restrict__ A_log,
                               const float* __restrict__ dt_bias, float* __restrict__ ACS,
                               float* __restrict__ DTV, float* __restrict__ DASUM){
  int c=blockIdx.x, h=blockIdx.y, b=blockIdx.z, tid=threadIdx.x;
  __shared__ float acs[CHUNK];
  size_t base = ((size_t)b*NHEADS+h)*LSP + c*CHUNK + tid;
  float raw = bf2f(DT[base]);
  float dtv = softplusf(raw + dt_bias[h]);
  float Ah = -__expf(A_log[h]);
  acs[tid] = dtv*Ah*LOG2E;   // pre-scaled: downstream uses exp2
  __syncthreads();
  for(int o=1;o<256;o<<=1){
    float add=(tid>=o)?acs[tid-o]:0.f;
    __syncthreads(); acs[tid]+=add; __syncthreads();
  }
  ACS[base] = acs[tid];
  DTV[base] = dtv;
  if (tid==CHUNK-1) DASUM[((size_t)b*NHEADS+h)*NCHUNK+c] = acs[tid];
}

// ---------------- SSD states (MFMA): states_T[p][n] = sum_t Xdtw[t][p]*B[t][n] ------
__global__ __launch_bounds__(256,4) void ssd_states_mfma(
    const float* __restrict__ ACS, const float* __restrict__ DTV,
    const float* __restrict__ DASUM, const u16* __restrict__ XBC,
    float* __restrict__ STATES){
  int c=blockIdx.x, h=blockIdx.y, b=blockIdx.z;
  int tid=threadIdx.x, w=tid>>6, lane=tid&63, l15=lane&15, quad=lane>>4;
  __shared__ float wdt[CHUNK];
  __shared__ u16 Xw[64][136];
  __shared__ u16 Bn[64][136];
  {
    size_t base = ((size_t)b*NHEADS+h)*LSP + c*CHUNK + tid;
    float atot = DASUM[((size_t)b*NHEADS+h)*NCHUNK+c];
    wdt[tid] = DTV[base]*exp2g(atot - ACS[base]);
  }
  __syncthreads();
  f32x4 acc[4];
  #pragma unroll
  for(int i=0;i<4;i++) acc[i] = (f32x4){0.f,0.f,0.f,0.f};
  size_t cb = (size_t)c*CHUNK;
  for(int th=0; th<2; th++){
    __syncthreads();
    {
      int n=tid&63, q4=tid>>6;
      const u16* Xg = XBC + ((size_t)b*CONVDIM + h*HEADDIM + n)*LSP + cb + th*128;
      const u16* Bg = XBC + ((size_t)b*CONVDIM + DINNER + n)*LSP + cb + th*128;
      #pragma unroll
      for(int i=0;i<4;i++){
        int o = q4*32+i*8;
        u16x8 v = *(const u16x8*)&Xg[o];
        u16x8 wv;
        #pragma unroll
        for(int j=0;j<8;j++) wv[j]=f2bf(bf2f(v[j])*wdt[th*128+o+j]);
        *(u16x8*)&Xw[n][o]=wv;
        *(u16x8*)&Bn[n][o] = *(const u16x8*)&Bg[o];
      }
    }
    __syncthreads();
    #pragma unroll
    for(int k8=0;k8<4;k8++){
      u16x8 a = *(const u16x8*)&Xw[w*16+l15][k8*32+quad*8];
      #pragma unroll
      for(int nt=0;nt<4;nt++){
        u16x8 bb = *(const u16x8*)&Bn[nt*16+l15][k8*32+quad*8];
        acc[nt]=MFMA16(a,bb,acc[nt]);
      }
    }
  }
  float* dst = STATES + (((size_t)b*NHEADS+h)*NCHUNK+c)*4096;
  #pragma unroll
  for(int nt=0;nt<4;nt++)
    #pragma unroll
    for(int r=0;r<4;r++)
      dst[(w*16+quad*4+r)*64 + nt*16+l15] = acc[nt][r];
}

// ---------------- inter-chunk scan -> PREVB bf16 [p][n] per (b,h,c) ----------------
__global__ void ssd_scan_kernel(const float* __restrict__ STATES, const float* __restrict__ DASUM,
                                u16* __restrict__ PREVB){
  int g = blockIdx.x, h = blockIdx.y, b = blockIdx.z, tid = threadIdx.x;
  int e = g*256 + tid;
  size_t hb = (size_t)b*NHEADS + h;
  size_t base = hb*NCHUNK*4096 + e;
  float s = 0.f;
  for (int cc=0;cc<NCHUNK;cc++){
    PREVB[base + (size_t)cc*4096] = f2bf(s);
    s = s*exp2g(DASUM[hb*NCHUNK + cc]) + STATES[base + (size_t)cc*4096];
  }
}

// ---------------- SSD Y (MFMA, band per block, 2 HEADS per block, v2) --------------
// S = C.B^T head-independent, computed once. Xs LDS removed (X is already [p][s]-major
// in XBC -> direct global fragment loads). Single shared Ps (heads sequential,
// wave-local rows). Bs double-buffered -> ONE barrier per sb. Yo folded into Yd init
// (eat known at prologue). LDS = 31744 B -> 5 blocks/CU.
__global__ __launch_bounds__(256,5) void ssd_y_mfma(
    const float* __restrict__ ACS, const float* __restrict__ DTV,
    const u16* __restrict__ XBC, const float* __restrict__ Dp,
    const u16* __restrict__ PREVB, const u16* __restrict__ ZT,
    u16* __restrict__ YG){
  int hp = blockIdx.x, bx = blockIdx.y, b = blockIdx.z;
  int h0 = hp*2;
  int c = bx>>2, tb = 3-(bx&3);
  int tid=threadIdx.x, w=tid>>6, lane=tid&63, l15=lane&15, quad=lane>>4;
  // manual carve: [0,4096) acs/dtv f32[2][256] pairs; [4096,22528) Bs dbuf; [22528,31744) Ps
  __shared__ __align__(16) char smem[31744];
  float* acs2 = (float*)smem;           // [hh*256 + s]
  float* dtv2 = (float*)(smem+2048);
  typedef u16 u16row72[72];
  u16row72* BsA = (u16row72*)(smem+4096);
  u16row72* BsB = (u16row72*)(smem+4096+9216);
  u16row72* Ps  = (u16row72*)(smem+22528);
  {
    size_t base0 = ((size_t)b*NHEADS+h0)*LSP + c*CHUNK + tid;
    acs2[tid]     = ACS[base0];
    dtv2[tid]     = DTV[base0];
    acs2[256+tid] = ACS[base0+LSP];
    dtv2[256+tid] = DTV[base0+LSP];
  }
  // C fragment: once-per-block strided gather, shared by both heads
  u16x8 ca0, ca1;
  {
    const u16* Cbase = XBC + ((size_t)b*CONVDIM + DINNER + DSTATE)*LSP
                     + (size_t)c*CHUNK + tb*64 + w*16 + l15;
    #pragma unroll
    for(int j=0;j<8;j++){
      ca0[j] = Cbase[(size_t)(quad*8+j)*LSP];
      ca1[j] = Cbase[(size_t)(32+quad*8+j)*LSP];
    }
  }
  __syncthreads();
  int tloc = tb*64 + w*16 + quad*4;
  float acst[2][4], eat2[2][4];
  #pragma unroll
  for(int hh=0;hh<2;hh++)
    #pragma unroll
    for(int r=0;r<4;r++){
      acst[hh][r] = acs2[hh*256 + tloc + r];
      eat2[hh][r] = exp2g(acst[hh][r]);
    }
  float DhA[2] = { Dp[h0], Dp[h0+1] };
  // Yd init = eat * (C . prev)  (folds Y_off scaling into the accumulator)
  f32x4 Yd[2][4];
  #pragma unroll
  for(int hh=0;hh<2;hh++){
    const u16* Pg = PREVB + (((size_t)b*NHEADS+h0+hh)*NCHUNK + c)*4096;
    #pragma unroll
    for(int pt=0;pt<4;pt++){
      f32x4 yo = (f32x4){0.f,0.f,0.f,0.f};
      u16x8 b0 = *(const u16x8*)&Pg[(pt*16+l15)*64 + quad*8];
      u16x8 b1 = *(const u16x8*)&Pg[(pt*16+l15)*64 + 32 + quad*8];
      yo = MFMA16(ca0,b0,yo);
      yo = MFMA16(ca1,b1,yo);
      #pragma unroll
      for(int r=0;r<4;r++) Yd[hh][pt][r] = eat2[hh][r]*yo[r];
    }
  }
  const u16* Bgbase = XBC + ((size_t)b*CONVDIM + DINNER)*LSP + (size_t)c*CHUNK;
  for(int sb=0; sb<=tb; sb++){
    u16row72* Bsb = (sb&1) ? BsB : BsA;
    // stage B (transpose [n][s] -> [s][n]) into this iteration's buffer
    {
      int n=tid&63, q4=tid>>6;
      const u16* Bg = Bgbase + (size_t)n*LSP + sb*64;
      #pragma unroll
      for(int i=0;i<2;i++){
        u16x8 v = *(const u16x8*)&Bg[q4*16+i*8];
        #pragma unroll
        for(int j=0;j<8;j++) Bsb[q4*16+i*8+j][n]=v[j];
      }
    }
    __syncthreads();
    // S = C.B^T (head-independent, computed once)
    f32x4 S[4];
    #pragma unroll
    for(int st=0;st<4;st++){
      S[st]=(f32x4){0.f,0.f,0.f,0.f};
      u16x8 b0 = *(const u16x8*)&Bsb[st*16+l15][quad*8];
      u16x8 b1 = *(const u16x8*)&Bsb[st*16+l15][32+quad*8];
      S[st]=MFMA16(ca0,b0,S[st]);
      S[st]=MFMA16(ca1,b1,S[st]);
    }
    // per-head: decay/dt transform -> P (shared buffer, wave-local rows) -> Yd MFMAs
    #pragma unroll
    for(int hh=0;hh<2;hh++){
      float Dh = DhA[hh];
      const float* acsh = acs2 + hh*256;
      const float* dtvh = dtv2 + hh*256;
      if (sb < tb){
        #pragma unroll
        for(int st=0;st<4;st++){
          int s = sb*64 + st*16 + l15;
          float as = acsh[s], dv = dtvh[s];
          #pragma unroll
          for(int r=0;r<4;r++)
            Ps[w*16+quad*4+r][st*16+l15] = f2bf(S[st][r]*exp2g(acst[hh][r]-as)*dv);
        }
      } else {
        #pragma unroll
        for(int st=0;st<4;st++){
          int s = sb*64 + st*16 + l15;
          float as = acsh[s], dv = dtvh[s];
          #pragma unroll
          for(int r=0;r<4;r++){
            int t = tloc + r;
            float pv;
            if (s < t)       pv = S[st][r]*exp2g(acst[hh][r]-as)*dv;
            else if (s == t) pv = S[st][r]*dv + Dh;
            else             pv = 0.f;
            Ps[w*16+quad*4+r][st*16+l15] = f2bf(pv);
          }
        }
      }
      u16x8 p0 = *(const u16x8*)&Ps[w*16+l15][quad*8];
      u16x8 p1 = *(const u16x8*)&Ps[w*16+l15][32+quad*8];
      // X fragments straight from global (XBC is [p][s]-major = B-operand layout)
      const u16* Xg = XBC + ((size_t)b*CONVDIM + (h0+hh)*HEADDIM)*LSP
                    + (size_t)c*CHUNK + sb*64;
      #pragma unroll
      for(int pt=0;pt<4;pt++){
        const u16* xr = Xg + (size_t)(pt*16+l15)*LSP + quad*8;
        u16x8 x0 = *(const u16x8*)&xr[0];
        u16x8 x1 = *(const u16x8*)&xr[32];
        Yd[hh][pt]=MFMA16(p0,x0,Yd[hh][pt]);
        Yd[hh][pt]=MFMA16(p1,x1,Yd[hh][pt]);
      }
    }
  }
  // epilogue: stage Y as f32 in smem (per head, sequential), coalesced ZT/YG pass
  __syncthreads();
  typedef float f32row66[66];
  f32row66* Yf = (f32row66*)smem;   // 64*66*4 = 16896 B <= 31744
  #pragma unroll
  for(int hh=0;hh<2;hh++){
    #pragma unroll
    for(int pt=0;pt<4;pt++)
      #pragma unroll
      for(int r=0;r<4;r++)
        Yf[w*16+quad*4+r][pt*16+l15] = Yd[hh][pt][r];
    __syncthreads();
    {
      int row = tid>>2, seg = tid&3;
      size_t lrow = (size_t)b*LSP + (size_t)c*CHUNK + tb*64 + row;
      size_t oi = lrow*DINNER + (size_t)(h0+hh)*HEADDIM + seg*16;
      u16x8 z0 = *(const u16x8*)&ZT[oi];
      u16x8 z1 = *(const u16x8*)&ZT[oi+8];
      u16x8 o0, o1;
      #pragma unroll
      for(int j=0;j<8;j++){
        o0[j] = f2bf(Yf[row][seg*16+j]   * siluf(bf2f(z0[j])));
        o1[j] = f2bf(Yf[row][seg*16+8+j] * siluf(bf2f(z1[j])));
      }
      *(u16x8*)&YG[oi]   = o0;
      *(u16x8*)&YG[oi+8] = o1;
    }
    if (hh==0) __syncthreads();
  }
}

extern "C" void kernel_launch(void* const* d_in, const int* in_sizes, int n_in,
                              void* d_out, int out_size, void* d_ws, size_t ws_size,
                              hipStream_t stream) {
  const float* x     = (const float*)d_in[0];
  const float* lnw   = (const float*)d_in[1];
  const float* lnb   = (const float*)d_in[2];
  const float* inpw  = (const float*)d_in[3];
  const float* convw = (const float*)d_in[4];
  const float* convb = (const float*)d_in[5];
  const float* alog  = (const float*)d_in[6];
  const float* Dp    = (const float*)d_in[7];
  const float* dtbi  = (const float*)d_in[8];
  const float* rmsw  = (const float*)d_in[9];
  const float* outw  = (const float*)d_in[10];
  float* out = (float*)d_out;

  char* ws = (char*)d_ws;
  size_t off = 0;
  auto alloc = [&](size_t bytes)->void*{ void* p = ws+off; off += (bytes+255)&~(size_t)255; return p; };
  u16*   WPIN   = (u16*)  alloc((size_t)MPAD*DIMC*2);
  u16*   WPOUT  = (u16*)  alloc((size_t)DIMC*DINNER*2);
  char*  RA     = (char*) alloc((size_t)BATCH*NHEADS*NCHUNK*4096*4);
  u16*   XNT    = (u16*)RA;
  float* STATES = (float*)RA;
  u16*   ZT     = (u16*)  alloc((size_t)BATCH*LSP*DINNER*2);
  u16*   XBC    = (u16*)  alloc((size_t)BATCH*CONVDIM*LSP*2);
  u16*   DTb    = (u16*)  alloc((size_t)BATCH*NHEADS*LSP*2);
  u16*   PREVB  = (u16*)  alloc((size_t)BATCH*NHEADS*NCHUNK*4096*2);
  float* DASUM  = (float*)alloc((size_t)BATCH*NHEADS*NCHUNK*4);
  float* ACS    = (float*)alloc((size_t)BATCH*NHEADS*LSP*4);
  float* DTV    = (float*)alloc((size_t)BATCH*NHEADS*LSP*4);
  u16*   YG     = (u16*)  alloc((size_t)BATCH*LSP*DINNER*2);

  convert_w<<<(MPAD*DIMC+255)/256,256,0,stream>>>(inpw, WPIN, MPAD*DIMC, DPROJ*DIMC);
  convert_w_rms<<<(DIMC*DINNER+255)/256,256,0,stream>>>(outw, rmsw, WPOUT);
  ln_kernel<<<dim3(BATCH*LSP/256),256,0,stream>>>(x,lnw,lnb,XNT);
  gemm_in_fused<<<dim3(LSP/128,2,BATCH),256,0,stream>>>(WPIN, XNT, ZT, XBC, DTb);
  conv_kernel<<<dim3(CONVDIM,BATCH),256,0,stream>>>(XBC, convw, convb);
  ssd_pre_kernel<<<dim3(NCHUNK,NHEADS,BATCH),256,0,stream>>>(DTb, alog, dtbi, ACS, DTV, DASUM);
  ssd_states_mfma<<<dim3(NCHUNK,NHEADS,BATCH),256,0,stream>>>(ACS,DTV,DASUM,XBC,STATES);
  ssd_scan_kernel<<<dim3(16,NHEADS,BATCH),256,0,stream>>>(STATES,DASUM,PREVB);
  ssd_y_mfma<<<dim3(NHEADS/2,NCHUNK*4,BATCH),256,0,stream>>>(ACS,DTV,XBC,Dp,PREVB,ZT,YG);
  gemm_out_mfma<<<dim3(LSP/128,DIMC/128,BATCH),256,0,stream>>>(WPOUT, YG, x, out);
}

// Round 4
// 346.250 us; speedup vs baseline: 1.1102x; 1.1102x over previous
//
#include <hip/hip_runtime.h>
#include <hip/hip_bf16.h>
#include <math.h>

#define DIMC   256
#define LSP    4096
#define BATCH  8
#define DINNER 512
#define NHEADS 8
#define HEADDIM 64
#define DSTATE 64
#define CONVDIM 640
#define DPROJ  1160
#define MPAD   1280
#define CHUNK  256
#define NCHUNK 16
#define LOG2E  1.44269504088896f

typedef unsigned short u16;
typedef __attribute__((ext_vector_type(8))) unsigned short u16x8;
typedef __attribute__((ext_vector_type(8))) short s16x8;
typedef __attribute__((ext_vector_type(4))) float f32x4;

#define MFMA16(a,b,c) __builtin_amdgcn_mfma_f32_16x16x32_bf16((s16x8)(a),(s16x8)(b),(c),0,0,0)

__device__ __forceinline__ float bf2f(u16 u){ return __uint_as_float(((unsigned int)u)<<16); }
__device__ __forceinline__ u16 f2bf(float f){
  unsigned int x = __float_as_uint(f);
  unsigned int r = (x + 0x7fffu + ((x>>16)&1u)) >> 16;
  return (u16)r;
}
__device__ __forceinline__ float exp2g(float x){ return __builtin_amdgcn_exp2f(x); }
__device__ __forceinline__ float softplusf(float x){ return (x > 20.f) ? x : __logf(1.f + __expf(x)); }
__device__ __forceinline__ float siluf(float x){ return x * __builtin_amdgcn_rcpf(1.f + __expf(-x)); }

// ---------------- weight fp32 -> bf16 (with trailing-row zero pad) ----------------
__global__ void convert_w(const float* __restrict__ src, u16* __restrict__ dst,
                          int total, int valid){
  int i = blockIdx.x*256 + threadIdx.x;
  if (i >= total) return;
  dst[i] = (i < valid) ? f2bf(src[i]) : (u16)0;
}

// ---------------- out_proj weight * rmsw fold -> bf16 ----------------
__global__ void convert_w_rms(const float* __restrict__ src, const float* __restrict__ rmsw,
                              u16* __restrict__ dst){
  int i = blockIdx.x*256 + threadIdx.x;
  if (i >= DIMC*DINNER) return;
  dst[i] = f2bf(src[i] * rmsw[i & (DINNER-1)]);
}

// ---------------- LayerNorm: x [b][c][l] fp32 -> XNT [b][l][c] bf16 ----------------
__global__ void ln_kernel(const float* __restrict__ X, const float* __restrict__ lnw,
                          const float* __restrict__ lnb, u16* __restrict__ XNT) {
  int pos = blockIdx.x*256 + threadIdx.x;
  int b = pos >> 12, l = pos & (LSP-1);
  const float* xb = X + ((size_t)b*DIMC)*LSP + l;
  float sum=0.f, sq=0.f;
  for (int c=0;c<DIMC;c++){ float v=xb[(size_t)c*LSP]; sum+=v; sq+=v*v; }
  float mu = sum*(1.f/DIMC);
  float var = sq*(1.f/DIMC) - mu*mu;
  float rs = rsqrtf(var + 1e-5f);
  u16* ob = XNT + ((size_t)(b*LSP + l))*DIMC;
  for (int c0=0;c0<DIMC;c0+=8){
    u16x8 v8;
    #pragma unroll
    for(int j=0;j<8;j++){
      float v = xb[(size_t)(c0+j)*LSP];
      v8[j] = f2bf((v-mu)*rs*lnw[c0+j] + lnb[c0+j]);
    }
    *(u16x8*)&ob[c0] = v8;
  }
}

// ---------------- Fused in_proj GEMM: XNT tile LDS-resident, loop over 5 proj tiles.
__global__ __launch_bounds__(256,2) void gemm_in_fused(
    const u16* __restrict__ W, const u16* __restrict__ XNT,
    u16* __restrict__ ZT, u16* __restrict__ XBC, u16* __restrict__ DT){
  __shared__ u16 Xs[128][264];
  __shared__ u16 Ws[128][32];
  int tid=threadIdx.x, w=tid>>6, lane=tid&63, l15=lane&15, quad=lane>>4;
  int n0=blockIdx.x*128, mh=blockIdx.y, b=blockIdx.z;
  {
    const u16* src = XNT + ((size_t)(b*LSP + n0))*DIMC;
    #pragma unroll
    for (int i=0;i<16;i++){
      int g = i*256 + tid;
      int row = g>>5, c8 = (g&31)*8;
      *(u16x8*)&Xs[row][c8] = *(const u16x8*)&src[(size_t)row*DIMC + c8];
    }
  }
  for (int pti=0; pti<5; pti++){
    int ptg = mh*5 + pti;
    int m0 = ptg*128;
    f32x4 acc[4][4];
    #pragma unroll
    for(int i=0;i<4;i++)
      #pragma unroll
      for(int j=0;j<4;j++) acc[i][j]=(f32x4){0.f,0.f,0.f,0.f};
    for (int k0=0;k0<DIMC;k0+=32){
      __syncthreads();
      {
        int ch = tid*2;
        int r = ch>>2, o=(ch&3)*8;
        *(u16x8*)&Ws[r][o] = *(const u16x8*)&W[(size_t)(m0+r)*DIMC + k0 + o];
        ch++; r = ch>>2; o=(ch&3)*8;
        *(u16x8*)&Ws[r][o] = *(const u16x8*)&W[(size_t)(m0+r)*DIMC + k0 + o];
      }
      __syncthreads();
      u16x8 af[4], bfr[4];
      if (ptg < 4){
        #pragma unroll
        for(int mt=0;mt<4;mt++) af[mt] = *(const u16x8*)&Xs[(w>>1)*64+mt*16+l15][k0+quad*8];
        #pragma unroll
        for(int nt=0;nt<4;nt++) bfr[nt] = *(const u16x8*)&Ws[(w&1)*64+nt*16+l15][quad*8];
      } else {
        #pragma unroll
        for(int mt=0;mt<4;mt++) af[mt] = *(const u16x8*)&Ws[(w>>1)*64+mt*16+l15][quad*8];
        #pragma unroll
        for(int nt=0;nt<4;nt++) bfr[nt] = *(const u16x8*)&Xs[(w&1)*64+nt*16+l15][k0+quad*8];
      }
      #pragma unroll
      for(int mt=0;mt<4;mt++)
        #pragma unroll
        for(int nt=0;nt<4;nt++)
          acc[mt][nt]=MFMA16(af[mt],bfr[nt],acc[mt][nt]);
    }
    if (ptg < 4){
      #pragma unroll
      for(int mt=0;mt<4;mt++)
        #pragma unroll
        for(int nt=0;nt<4;nt++)
          #pragma unroll
          for(int r=0;r<4;r++){
            int lrow = n0 + (w>>1)*64 + mt*16 + quad*4 + r;
            int dcol = m0 + (w&1)*64 + nt*16 + l15;
            ZT[((size_t)b*LSP + lrow)*DINNER + dcol] = f2bf(acc[mt][nt][r]);
          }
    } else {
      #pragma unroll
      for(int mt=0;mt<4;mt++)
        #pragma unroll
        for(int nt=0;nt<4;nt++)
          #pragma unroll
          for(int r=0;r<4;r++){
            int prow = m0 + (w>>1)*64 + mt*16 + quad*4 + r;
            if (prow>=DPROJ) continue;
            int col = n0 + (w&1)*64 + nt*16 + l15;
            u16 v = f2bf(acc[mt][nt][r]);
            if (prow<DINNER+CONVDIM)  XBC[((size_t)b*CONVDIM+(prow-DINNER))*LSP+col]=v;
            else                      DT[((size_t)b*NHEADS+(prow-DINNER-CONVDIM))*LSP+col]=v;
          }
    }
  }
}

// ---------------- GEMM2 (MFMA): W2' [256x512] x g [b,l,512]; rms folded into loader ---
__global__ void gemm_out_mfma(const u16* __restrict__ A, const u16* __restrict__ Bm,
                              const float* __restrict__ Res, float* __restrict__ Out){
  __shared__ u16 As[128][32];
  __shared__ u16 Bs[128][32];
  __shared__ float rinv[128];
  int tid=threadIdx.x, w=tid>>6, lane=tid&63, l15=lane&15, quad=lane>>4;
  int b=blockIdx.z, m0=blockIdx.y*128, n0=blockIdx.x*128;
  const u16* Bb = Bm + ((size_t)b*LSP + n0)*DINNER;
  f32x4 acc[4][4];
  #pragma unroll
  for(int i=0;i<4;i++)
    #pragma unroll
    for(int j=0;j<4;j++) acc[i][j] = (f32x4){0.f,0.f,0.f,0.f};
  float sqacc = 0.f;
  for (int k0=0;k0<DINNER;k0+=32){
    __syncthreads();
    {
      int ch = tid*2;
      int r = ch>>2, o=(ch&3)*8;
      *(u16x8*)&As[r][o] = *(const u16x8*)&A[(size_t)(m0+r)*DINNER + k0 + o];
      u16x8 bv = *(const u16x8*)&Bb[(size_t)r*DINNER + k0 + o];
      *(u16x8*)&Bs[r][o] = bv;
      #pragma unroll
      for(int j=0;j<8;j++){ float f=bf2f(bv[j]); sqacc += f*f; }
      ch++; r = ch>>2; o=(ch&3)*8;
      *(u16x8*)&As[r][o] = *(const u16x8*)&A[(size_t)(m0+r)*DINNER + k0 + o];
      u16x8 bv2 = *(const u16x8*)&Bb[(size_t)r*DINNER + k0 + o];
      *(u16x8*)&Bs[r][o] = bv2;
      #pragma unroll
      for(int j=0;j<8;j++){ float f=bf2f(bv2[j]); sqacc += f*f; }
    }
    __syncthreads();
    u16x8 af[4], bfr[4];
    #pragma unroll
    for(int mt=0;mt<4;mt++) af[mt] = *(const u16x8*)&As[(w>>1)*64+mt*16+l15][quad*8];
    #pragma unroll
    for(int nt=0;nt<4;nt++) bfr[nt] = *(const u16x8*)&Bs[(w&1)*64+nt*16+l15][quad*8];
    #pragma unroll
    for(int mt=0;mt<4;mt++)
      #pragma unroll
      for(int nt=0;nt<4;nt++)
        acc[mt][nt]=MFMA16(af[mt],bfr[nt],acc[mt][nt]);
  }
  // pair (tid, tid^1) covers one g-row; reduce and publish rinv
  {
    float tot = sqacc + __shfl_xor(sqacc, 1, 64);
    if ((tid&1)==0) rinv[tid>>1] = rsqrtf(tot*(1.f/DINNER) + 1e-5f);
  }
  __syncthreads();
  #pragma unroll
  for(int mt=0;mt<4;mt++)
    #pragma unroll
    for(int nt=0;nt<4;nt++){
      float rv = rinv[(w&1)*64 + nt*16 + l15];
      #pragma unroll
      for(int r=0;r<4;r++){
        int row = m0 + (w>>1)*64 + mt*16 + quad*4 + r;
        int col = n0 + (w&1)*64 + nt*16 + l15;
        size_t oi = ((size_t)b*DIMC+row)*LSP+col;
        Out[oi] = acc[mt][nt][r]*rv + Res[oi];
      }
    }
}

// ---------------- Depthwise 3x3 conv + bias + SiLU, IN-PLACE on XBC ----------------
__global__ void conv_kernel(u16* __restrict__ XBC, const float* __restrict__ CW,
                            const float* __restrict__ CB){
  int ch = blockIdx.x, b = blockIdx.y, tid = threadIdx.x;
  __shared__ float plane[66*66];
  u16* base = XBC + ((size_t)b*CONVDIM + ch)*LSP;
  for (int idx=tid; idx<66*66; idx+=256){
    int yy = idx/66 - 1, xx = idx%66 - 1;
    float v = 0.f;
    if (yy>=0 && yy<64 && xx>=0 && xx<64) v = bf2f(base[yy*64+xx]);
    plane[idx] = v;
  }
  float wg[9];
  #pragma unroll
  for (int t=0;t<9;t++) wg[t] = CW[ch*9+t];
  float bias = CB[ch];
  __syncthreads();
  for (int r=0;r<16;r++){
    int pix = tid + r*256;
    int y = pix>>6, x = pix&63;
    float s=0.f;
    #pragma unroll
    for(int dy=0;dy<3;dy++)
      #pragma unroll
      for(int dx=0;dx<3;dx++) s += plane[(y+dy)*66 + x+dx]*wg[dy*3+dx];
    base[pix] = f2bf(siluf(s + bias));
  }
}

// ---------------- SSD pre: dt softplus + per-chunk cumsum (LOG2E-scaled), ONCE ------
__global__ void ssd_pre_kernel(const u16* __restrict__ DT, const float* __restrict__ A_log,
                               const float* __restrict__ dt_bias, float* __restrict__ ACS,
                               float* __restrict__ DTV, float* __restrict__ DASUM){
  int c=blockIdx.x, h=blockIdx.y, b=blockIdx.z, tid=threadIdx.x;
  __shared__ float acs[CHUNK];
  size_t base = ((size_t)b*NHEADS+h)*LSP + c*CHUNK + tid;
  float raw = bf2f(DT[base]);
  float dtv = softplusf(raw + dt_bias[h]);
  float Ah = -__expf(A_log[h]);
  acs[tid] = dtv*Ah*LOG2E;   // pre-scaled: downstream uses exp2
  __syncthreads();
  for(int o=1;o<256;o<<=1){
    float add=(tid>=o)?acs[tid-o]:0.f;
    __syncthreads(); acs[tid]+=add; __syncthreads();
  }
  ACS[base] = acs[tid];
  DTV[base] = dtv;
  if (tid==CHUNK-1) DASUM[((size_t)b*NHEADS+h)*NCHUNK+c] = acs[tid];
}

// ---------------- SSD states (MFMA): states_T[p][n] = sum_t Xdtw[t][p]*B[t][n] ------
__global__ __launch_bounds__(256,4) void ssd_states_mfma(
    const float* __restrict__ ACS, const float* __restrict__ DTV,
    const float* __restrict__ DASUM, const u16* __restrict__ XBC,
    float* __restrict__ STATES){
  int c=blockIdx.x, h=blockIdx.y, b=blockIdx.z;
  int tid=threadIdx.x, w=tid>>6, lane=tid&63, l15=lane&15, quad=lane>>4;
  __shared__ float wdt[CHUNK];
  __shared__ u16 Xw[64][136];
  __shared__ u16 Bn[64][136];
  {
    size_t base = ((size_t)b*NHEADS+h)*LSP + c*CHUNK + tid;
    float atot = DASUM[((size_t)b*NHEADS+h)*NCHUNK+c];
    wdt[tid] = DTV[base]*exp2g(atot - ACS[base]);
  }
  __syncthreads();
  f32x4 acc[4];
  #pragma unroll
  for(int i=0;i<4;i++) acc[i] = (f32x4){0.f,0.f,0.f,0.f};
  size_t cb = (size_t)c*CHUNK;
  for(int th=0; th<2; th++){
    __syncthreads();
    {
      int n=tid&63, q4=tid>>6;
      const u16* Xg = XBC + ((size_t)b*CONVDIM + h*HEADDIM + n)*LSP + cb + th*128;
      const u16* Bg = XBC + ((size_t)b*CONVDIM + DINNER + n)*LSP + cb + th*128;
      #pragma unroll
      for(int i=0;i<4;i++){
        int o = q4*32+i*8;
        u16x8 v = *(const u16x8*)&Xg[o];
        u16x8 wv;
        #pragma unroll
        for(int j=0;j<8;j++) wv[j]=f2bf(bf2f(v[j])*wdt[th*128+o+j]);
        *(u16x8*)&Xw[n][o]=wv;
        *(u16x8*)&Bn[n][o] = *(const u16x8*)&Bg[o];
      }
    }
    __syncthreads();
    #pragma unroll
    for(int k8=0;k8<4;k8++){
      u16x8 a = *(const u16x8*)&Xw[w*16+l15][k8*32+quad*8];
      #pragma unroll
      for(int nt=0;nt<4;nt++){
        u16x8 bb = *(const u16x8*)&Bn[nt*16+l15][k8*32+quad*8];
        acc[nt]=MFMA16(a,bb,acc[nt]);
      }
    }
  }
  float* dst = STATES + (((size_t)b*NHEADS+h)*NCHUNK+c)*4096;
  #pragma unroll
  for(int nt=0;nt<4;nt++)
    #pragma unroll
    for(int r=0;r<4;r++)
      dst[(w*16+quad*4+r)*64 + nt*16+l15] = acc[nt][r];
}

// ---------------- inter-chunk scan -> PREVB bf16 [p][n] per (b,h,c) ----------------
__global__ void ssd_scan_kernel(const float* __restrict__ STATES, const float* __restrict__ DASUM,
                                u16* __restrict__ PREVB){
  int g = blockIdx.x, h = blockIdx.y, b = blockIdx.z, tid = threadIdx.x;
  int e = g*256 + tid;
  size_t hb = (size_t)b*NHEADS + h;
  size_t base = hb*NCHUNK*4096 + e;
  float s = 0.f;
  for (int cc=0;cc<NCHUNK;cc++){
    PREVB[base + (size_t)cc*4096] = f2bf(s);
    s = s*exp2g(DASUM[hb*NCHUNK + cc]) + STATES[base + (size_t)cc*4096];
  }
}

// ---------------- SSD Y (MFMA, band per block, 2 HEADS per block, v3) --------------
// v2 structure (1 barrier/sb, direct-global X, shared S, folded Yo) but
// __launch_bounds__(256,4): v2's (256,5) capped unified VGPR+AGPR at ~96 and
// spilled accumulators to scratch (WRITE_SIZE 33->142 MB). 4 blocks/CU = 128 regs.
__global__ __launch_bounds__(256,4) void ssd_y_mfma(
    const float* __restrict__ ACS, const float* __restrict__ DTV,
    const u16* __restrict__ XBC, const float* __restrict__ Dp,
    const u16* __restrict__ PREVB, const u16* __restrict__ ZT,
    u16* __restrict__ YG){
  int hp = blockIdx.x, bx = blockIdx.y, b = blockIdx.z;
  int h0 = hp*2;
  int c = bx>>2, tb = 3-(bx&3);
  int tid=threadIdx.x, w=tid>>6, lane=tid&63, l15=lane&15, quad=lane>>4;
  // manual carve: [0,4096) acs/dtv f32[2][256] pairs; [4096,22528) Bs dbuf; [22528,31744) Ps
  __shared__ __align__(16) char smem[31744];
  float* acs2 = (float*)smem;           // [hh*256 + s]
  float* dtv2 = (float*)(smem+2048);
  typedef u16 u16row72[72];
  u16row72* BsA = (u16row72*)(smem+4096);
  u16row72* BsB = (u16row72*)(smem+4096+9216);
  u16row72* Ps  = (u16row72*)(smem+22528);
  {
    size_t base0 = ((size_t)b*NHEADS+h0)*LSP + c*CHUNK + tid;
    acs2[tid]     = ACS[base0];
    dtv2[tid]     = DTV[base0];
    acs2[256+tid] = ACS[base0+LSP];
    dtv2[256+tid] = DTV[base0+LSP];
  }
  // C fragment: once-per-block strided gather, shared by both heads
  u16x8 ca0, ca1;
  {
    const u16* Cbase = XBC + ((size_t)b*CONVDIM + DINNER + DSTATE)*LSP
                     + (size_t)c*CHUNK + tb*64 + w*16 + l15;
    #pragma unroll
    for(int j=0;j<8;j++){
      ca0[j] = Cbase[(size_t)(quad*8+j)*LSP];
      ca1[j] = Cbase[(size_t)(32+quad*8+j)*LSP];
    }
  }
  __syncthreads();
  int tloc = tb*64 + w*16 + quad*4;
  float acst[2][4], eat2[2][4];
  #pragma unroll
  for(int hh=0;hh<2;hh++)
    #pragma unroll
    for(int r=0;r<4;r++){
      acst[hh][r] = acs2[hh*256 + tloc + r];
      eat2[hh][r] = exp2g(acst[hh][r]);
    }
  float DhA[2] = { Dp[h0], Dp[h0+1] };
  // Yd init = eat * (C . prev)  (folds Y_off scaling into the accumulator)
  f32x4 Yd[2][4];
  #pragma unroll
  for(int hh=0;hh<2;hh++){
    const u16* Pg = PREVB + (((size_t)b*NHEADS+h0+hh)*NCHUNK + c)*4096;
    #pragma unroll
    for(int pt=0;pt<4;pt++){
      f32x4 yo = (f32x4){0.f,0.f,0.f,0.f};
      u16x8 b0 = *(const u16x8*)&Pg[(pt*16+l15)*64 + quad*8];
      u16x8 b1 = *(const u16x8*)&Pg[(pt*16+l15)*64 + 32 + quad*8];
      yo = MFMA16(ca0,b0,yo);
      yo = MFMA16(ca1,b1,yo);
      #pragma unroll
      for(int r=0;r<4;r++) Yd[hh][pt][r] = eat2[hh][r]*yo[r];
    }
  }
  const u16* Bgbase = XBC + ((size_t)b*CONVDIM + DINNER)*LSP + (size_t)c*CHUNK;
  for(int sb=0; sb<=tb; sb++){
    u16row72* Bsb = (sb&1) ? BsB : BsA;
    // stage B (transpose [n][s] -> [s][n]) into this iteration's buffer
    {
      int n=tid&63, q4=tid>>6;
      const u16* Bg = Bgbase + (size_t)n*LSP + sb*64;
      #pragma unroll
      for(int i=0;i<2;i++){
        u16x8 v = *(const u16x8*)&Bg[q4*16+i*8];
        #pragma unroll
        for(int j=0;j<8;j++) Bsb[q4*16+i*8+j][n]=v[j];
      }
    }
    __syncthreads();
    // S = C.B^T (head-independent, computed once)
    f32x4 S[4];
    #pragma unroll
    for(int st=0;st<4;st++){
      S[st]=(f32x4){0.f,0.f,0.f,0.f};
      u16x8 b0 = *(const u16x8*)&Bsb[st*16+l15][quad*8];
      u16x8 b1 = *(const u16x8*)&Bsb[st*16+l15][32+quad*8];
      S[st]=MFMA16(ca0,b0,S[st]);
      S[st]=MFMA16(ca1,b1,S[st]);
    }
    // per-head: decay/dt transform -> P (shared buffer, wave-local rows) -> Yd MFMAs
    #pragma unroll
    for(int hh=0;hh<2;hh++){
      float Dh = DhA[hh];
      const float* acsh = acs2 + hh*256;
      const float* dtvh = dtv2 + hh*256;
      if (sb < tb){
        #pragma unroll
        for(int st=0;st<4;st++){
          int s = sb*64 + st*16 + l15;
          float as = acsh[s], dv = dtvh[s];
          #pragma unroll
          for(int r=0;r<4;r++)
            Ps[w*16+quad*4+r][st*16+l15] = f2bf(S[st][r]*exp2g(acst[hh][r]-as)*dv);
        }
      } else {
        #pragma unroll
        for(int st=0;st<4;st++){
          int s = sb*64 + st*16 + l15;
          float as = acsh[s], dv = dtvh[s];
          #pragma unroll
          for(int r=0;r<4;r++){
            int t = tloc + r;
            float pv;
            if (s < t)       pv = S[st][r]*exp2g(acst[hh][r]-as)*dv;
            else if (s == t) pv = S[st][r]*dv + Dh;
            else             pv = 0.f;
            Ps[w*16+quad*4+r][st*16+l15] = f2bf(pv);
          }
        }
      }
      u16x8 p0 = *(const u16x8*)&Ps[w*16+l15][quad*8];
      u16x8 p1 = *(const u16x8*)&Ps[w*16+l15][32+quad*8];
      // X fragments straight from global (XBC is [p][s]-major = B-operand layout)
      const u16* Xg = XBC + ((size_t)b*CONVDIM + (h0+hh)*HEADDIM)*LSP
                    + (size_t)c*CHUNK + sb*64;
      #pragma unroll
      for(int pt=0;pt<4;pt++){
        const u16* xr = Xg + (size_t)(pt*16+l15)*LSP + quad*8;
        u16x8 x0 = *(const u16x8*)&xr[0];
        u16x8 x1 = *(const u16x8*)&xr[32];
        Yd[hh][pt]=MFMA16(p0,x0,Yd[hh][pt]);
        Yd[hh][pt]=MFMA16(p1,x1,Yd[hh][pt]);
      }
    }
  }
  // epilogue: stage Y as f32 in smem (per head, sequential), coalesced ZT/YG pass
  __syncthreads();
  typedef float f32row66[66];
  f32row66* Yf = (f32row66*)smem;   // 64*66*4 = 16896 B <= 31744
  #pragma unroll
  for(int hh=0;hh<2;hh++){
    #pragma unroll
    for(int pt=0;pt<4;pt++)
      #pragma unroll
      for(int r=0;r<4;r++)
        Yf[w*16+quad*4+r][pt*16+l15] = Yd[hh][pt][r];
    __syncthreads();
    {
      int row = tid>>2, seg = tid&3;
      size_t lrow = (size_t)b*LSP + (size_t)c*CHUNK + tb*64 + row;
      size_t oi = lrow*DINNER + (size_t)(h0+hh)*HEADDIM + seg*16;
      u16x8 z0 = *(const u16x8*)&ZT[oi];
      u16x8 z1 = *(const u16x8*)&ZT[oi+8];
      u16x8 o0, o1;
      #pragma unroll
      for(int j=0;j<8;j++){
        o0[j] = f2bf(Yf[row][seg*16+j]   * siluf(bf2f(z0[j])));
        o1[j] = f2bf(Yf[row][seg*16+8+j] * siluf(bf2f(z1[j])));
      }
      *(u16x8*)&YG[oi]   = o0;
      *(u16x8*)&YG[oi+8] = o1;
    }
    if (hh==0) __syncthreads();
  }
}

extern "C" void kernel_launch(void* const* d_in, const int* in_sizes, int n_in,
                              void* d_out, int out_size, void* d_ws, size_t ws_size,
                              hipStream_t stream) {
  const float* x     = (const float*)d_in[0];
  const float* lnw   = (const float*)d_in[1];
  const float* lnb   = (const float*)d_in[2];
  const float* inpw  = (const float*)d_in[3];
  const float* convw = (const float*)d_in[4];
  const float* convb = (const float*)d_in[5];
  const float* alog  = (const float*)d_in[6];
  const float* Dp    = (const float*)d_in[7];
  const float* dtbi  = (const float*)d_in[8];
  const float* rmsw  = (const float*)d_in[9];
  const float* outw  = (const float*)d_in[10];
  float* out = (float*)d_out;

  char* ws = (char*)d_ws;
  size_t off = 0;
  auto alloc = [&](size_t bytes)->void*{ void* p = ws+off; off += (bytes+255)&~(size_t)255; return p; };
  u16*   WPIN   = (u16*)  alloc((size_t)MPAD*DIMC*2);
  u16*   WPOUT  = (u16*)  alloc((size_t)DIMC*DINNER*2);
  char*  RA     = (char*) alloc((size_t)BATCH*NHEADS*NCHUNK*4096*4);
  u16*   XNT    = (u16*)RA;
  float* STATES = (float*)RA;
  u16*   ZT     = (u16*)  alloc((size_t)BATCH*LSP*DINNER*2);
  u16*   XBC    = (u16*)  alloc((size_t)BATCH*CONVDIM*LSP*2);
  u16*   DTb    = (u16*)  alloc((size_t)BATCH*NHEADS*LSP*2);
  u16*   PREVB  = (u16*)  alloc((size_t)BATCH*NHEADS*NCHUNK*4096*2);
  float* DASUM  = (float*)alloc((size_t)BATCH*NHEADS*NCHUNK*4);
  float* ACS    = (float*)alloc((size_t)BATCH*NHEADS*LSP*4);
  float* DTV    = (float*)alloc((size_t)BATCH*NHEADS*LSP*4);
  u16*   YG     = (u16*)  alloc((size_t)BATCH*LSP*DINNER*2);

  convert_w<<<(MPAD*DIMC+255)/256,256,0,stream>>>(inpw, WPIN, MPAD*DIMC, DPROJ*DIMC);
  convert_w_rms<<<(DIMC*DINNER+255)/256,256,0,stream>>>(outw, rmsw, WPOUT);
  ln_kernel<<<dim3(BATCH*LSP/256),256,0,stream>>>(x,lnw,lnb,XNT);
  gemm_in_fused<<<dim3(LSP/128,2,BATCH),256,0,stream>>>(WPIN, XNT, ZT, XBC, DTb);
  conv_kernel<<<dim3(CONVDIM,BATCH),256,0,stream>>>(XBC, convw, convb);
  ssd_pre_kernel<<<dim3(NCHUNK,NHEADS,BATCH),256,0,stream>>>(DTb, alog, dtbi, ACS, DTV, DASUM);
  ssd_states_mfma<<<dim3(NCHUNK,NHEADS,BATCH),256,0,stream>>>(ACS,DTV,DASUM,XBC,STATES);
  ssd_scan_kernel<<<dim3(16,NHEADS,BATCH),256,0,stream>>>(STATES,DASUM,PREVB);
  ssd_y_mfma<<<dim3(NHEADS/2,NCHUNK*4,BATCH),256,0,stream>>>(ACS,DTV,XBC,Dp,PREVB,ZT,YG);
  gemm_out_mfma<<<dim3(LSP/128,DIMC/128,BATCH),256,0,stream>>>(WPOUT, YG, x, out);
}

// Round 5
// 309.572 us; speedup vs baseline: 1.2417x; 1.1185x over previous
//
#include <hip/hip_runtime.h>
#include <hip/hip_bf16.h>
#include <math.h>

#define DIMC   256
#define LSP    4096
#define BATCH  8
#define DINNER 512
#define NHEADS 8
#define HEADDIM 64
#define DSTATE 64
#define CONVDIM 640
#define DPROJ  1160
#define MPAD   1280
#define CHUNK  256
#define NCHUNK 16
#define LOG2E  1.44269504088896f

typedef unsigned short u16;
typedef __attribute__((ext_vector_type(8))) unsigned short u16x8;
typedef __attribute__((ext_vector_type(8))) short s16x8;
typedef __attribute__((ext_vector_type(4))) float f32x4;

#define MFMA16(a,b,c) __builtin_amdgcn_mfma_f32_16x16x32_bf16((s16x8)(a),(s16x8)(b),(c),0,0,0)

__device__ __forceinline__ float bf2f(u16 u){ return __uint_as_float(((unsigned int)u)<<16); }
__device__ __forceinline__ u16 f2bf(float f){
  unsigned int x = __float_as_uint(f);
  unsigned int r = (x + 0x7fffu + ((x>>16)&1u)) >> 16;
  return (u16)r;
}
__device__ __forceinline__ float exp2g(float x){ return __builtin_amdgcn_exp2f(x); }
__device__ __forceinline__ float softplusf(float x){ return (x > 20.f) ? x : __logf(1.f + __expf(x)); }
__device__ __forceinline__ float siluf(float x){ return x * __builtin_amdgcn_rcpf(1.f + __expf(-x)); }

// ---------------- weight fp32 -> bf16 (with trailing-row zero pad) ----------------
__global__ void convert_w(const float* __restrict__ src, u16* __restrict__ dst,
                          int total, int valid){
  int i = blockIdx.x*256 + threadIdx.x;
  if (i >= total) return;
  dst[i] = (i < valid) ? f2bf(src[i]) : (u16)0;
}

// ---------------- out_proj weight * rmsw fold -> bf16 ----------------
__global__ void convert_w_rms(const float* __restrict__ src, const float* __restrict__ rmsw,
                              u16* __restrict__ dst){
  int i = blockIdx.x*256 + threadIdx.x;
  if (i >= DIMC*DINNER) return;
  dst[i] = f2bf(src[i] * rmsw[i & (DINNER-1)]);
}

// ---------------- LayerNorm: x [b][c][l] fp32 -> XNT [b][l][c] bf16 ----------------
__global__ void ln_kernel(const float* __restrict__ X, const float* __restrict__ lnw,
                          const float* __restrict__ lnb, u16* __restrict__ XNT) {
  int pos = blockIdx.x*256 + threadIdx.x;
  int b = pos >> 12, l = pos & (LSP-1);
  const float* xb = X + ((size_t)b*DIMC)*LSP + l;
  float sum=0.f, sq=0.f;
  for (int c=0;c<DIMC;c++){ float v=xb[(size_t)c*LSP]; sum+=v; sq+=v*v; }
  float mu = sum*(1.f/DIMC);
  float var = sq*(1.f/DIMC) - mu*mu;
  float rs = rsqrtf(var + 1e-5f);
  u16* ob = XNT + ((size_t)(b*LSP + l))*DIMC;
  for (int c0=0;c0<DIMC;c0+=8){
    u16x8 v8;
    #pragma unroll
    for(int j=0;j<8;j++){
      float v = xb[(size_t)(c0+j)*LSP];
      v8[j] = f2bf((v-mu)*rs*lnw[c0+j] + lnb[c0+j]);
    }
    *(u16x8*)&ob[c0] = v8;
  }
}

// ---------------- Fused in_proj GEMM: XNT tile LDS-resident, loop over 5 proj tiles.
__global__ __launch_bounds__(256,2) void gemm_in_fused(
    const u16* __restrict__ W, const u16* __restrict__ XNT,
    u16* __restrict__ ZT, u16* __restrict__ XBC, u16* __restrict__ DT){
  __shared__ u16 Xs[128][264];
  __shared__ u16 Ws[128][32];
  int tid=threadIdx.x, w=tid>>6, lane=tid&63, l15=lane&15, quad=lane>>4;
  int n0=blockIdx.x*128, mh=blockIdx.y, b=blockIdx.z;
  {
    const u16* src = XNT + ((size_t)(b*LSP + n0))*DIMC;
    #pragma unroll
    for (int i=0;i<16;i++){
      int g = i*256 + tid;
      int row = g>>5, c8 = (g&31)*8;
      *(u16x8*)&Xs[row][c8] = *(const u16x8*)&src[(size_t)row*DIMC + c8];
    }
  }
  for (int pti=0; pti<5; pti++){
    int ptg = mh*5 + pti;
    int m0 = ptg*128;
    f32x4 acc[4][4];
    #pragma unroll
    for(int i=0;i<4;i++)
      #pragma unroll
      for(int j=0;j<4;j++) acc[i][j]=(f32x4){0.f,0.f,0.f,0.f};
    for (int k0=0;k0<DIMC;k0+=32){
      __syncthreads();
      {
        int ch = tid*2;
        int r = ch>>2, o=(ch&3)*8;
        *(u16x8*)&Ws[r][o] = *(const u16x8*)&W[(size_t)(m0+r)*DIMC + k0 + o];
        ch++; r = ch>>2; o=(ch&3)*8;
        *(u16x8*)&Ws[r][o] = *(const u16x8*)&W[(size_t)(m0+r)*DIMC + k0 + o];
      }
      __syncthreads();
      u16x8 af[4], bfr[4];
      if (ptg < 4){
        #pragma unroll
        for(int mt=0;mt<4;mt++) af[mt] = *(const u16x8*)&Xs[(w>>1)*64+mt*16+l15][k0+quad*8];
        #pragma unroll
        for(int nt=0;nt<4;nt++) bfr[nt] = *(const u16x8*)&Ws[(w&1)*64+nt*16+l15][quad*8];
      } else {
        #pragma unroll
        for(int mt=0;mt<4;mt++) af[mt] = *(const u16x8*)&Ws[(w>>1)*64+mt*16+l15][quad*8];
        #pragma unroll
        for(int nt=0;nt<4;nt++) bfr[nt] = *(const u16x8*)&Xs[(w&1)*64+nt*16+l15][k0+quad*8];
      }
      #pragma unroll
      for(int mt=0;mt<4;mt++)
        #pragma unroll
        for(int nt=0;nt<4;nt++)
          acc[mt][nt]=MFMA16(af[mt],bfr[nt],acc[mt][nt]);
    }
    if (ptg < 4){
      #pragma unroll
      for(int mt=0;mt<4;mt++)
        #pragma unroll
        for(int nt=0;nt<4;nt++)
          #pragma unroll
          for(int r=0;r<4;r++){
            int lrow = n0 + (w>>1)*64 + mt*16 + quad*4 + r;
            int dcol = m0 + (w&1)*64 + nt*16 + l15;
            ZT[((size_t)b*LSP + lrow)*DINNER + dcol] = f2bf(acc[mt][nt][r]);
          }
    } else {
      #pragma unroll
      for(int mt=0;mt<4;mt++)
        #pragma unroll
        for(int nt=0;nt<4;nt++)
          #pragma unroll
          for(int r=0;r<4;r++){
            int prow = m0 + (w>>1)*64 + mt*16 + quad*4 + r;
            if (prow>=DPROJ) continue;
            int col = n0 + (w&1)*64 + nt*16 + l15;
            u16 v = f2bf(acc[mt][nt][r]);
            if (prow<DINNER+CONVDIM)  XBC[((size_t)b*CONVDIM+(prow-DINNER))*LSP+col]=v;
            else                      DT[((size_t)b*NHEADS+(prow-DINNER-CONVDIM))*LSP+col]=v;
          }
    }
  }
}

// ---------------- GEMM2 (MFMA): W2' [256x512] x g [b,l,512]; rms folded into loader ---
__global__ void gemm_out_mfma(const u16* __restrict__ A, const u16* __restrict__ Bm,
                              const float* __restrict__ Res, float* __restrict__ Out){
  __shared__ u16 As[128][32];
  __shared__ u16 Bs[128][32];
  __shared__ float rinv[128];
  int tid=threadIdx.x, w=tid>>6, lane=tid&63, l15=lane&15, quad=lane>>4;
  int b=blockIdx.z, m0=blockIdx.y*128, n0=blockIdx.x*128;
  const u16* Bb = Bm + ((size_t)b*LSP + n0)*DINNER;
  f32x4 acc[4][4];
  #pragma unroll
  for(int i=0;i<4;i++)
    #pragma unroll
    for(int j=0;j<4;j++) acc[i][j] = (f32x4){0.f,0.f,0.f,0.f};
  float sqacc = 0.f;
  for (int k0=0;k0<DINNER;k0+=32){
    __syncthreads();
    {
      int ch = tid*2;
      int r = ch>>2, o=(ch&3)*8;
      *(u16x8*)&As[r][o] = *(const u16x8*)&A[(size_t)(m0+r)*DINNER + k0 + o];
      u16x8 bv = *(const u16x8*)&Bb[(size_t)r*DINNER + k0 + o];
      *(u16x8*)&Bs[r][o] = bv;
      #pragma unroll
      for(int j=0;j<8;j++){ float f=bf2f(bv[j]); sqacc += f*f; }
      ch++; r = ch>>2; o=(ch&3)*8;
      *(u16x8*)&As[r][o] = *(const u16x8*)&A[(size_t)(m0+r)*DINNER + k0 + o];
      u16x8 bv2 = *(const u16x8*)&Bb[(size_t)r*DINNER + k0 + o];
      *(u16x8*)&Bs[r][o] = bv2;
      #pragma unroll
      for(int j=0;j<8;j++){ float f=bf2f(bv2[j]); sqacc += f*f; }
    }
    __syncthreads();
    u16x8 af[4], bfr[4];
    #pragma unroll
    for(int mt=0;mt<4;mt++) af[mt] = *(const u16x8*)&As[(w>>1)*64+mt*16+l15][quad*8];
    #pragma unroll
    for(int nt=0;nt<4;nt++) bfr[nt] = *(const u16x8*)&Bs[(w&1)*64+nt*16+l15][quad*8];
    #pragma unroll
    for(int mt=0;mt<4;mt++)
      #pragma unroll
      for(int nt=0;nt<4;nt++)
        acc[mt][nt]=MFMA16(af[mt],bfr[nt],acc[mt][nt]);
  }
  // pair (tid, tid^1) covers one g-row; reduce and publish rinv
  {
    float tot = sqacc + __shfl_xor(sqacc, 1, 64);
    if ((tid&1)==0) rinv[tid>>1] = rsqrtf(tot*(1.f/DINNER) + 1e-5f);
  }
  __syncthreads();
  #pragma unroll
  for(int mt=0;mt<4;mt++)
    #pragma unroll
    for(int nt=0;nt<4;nt++){
      float rv = rinv[(w&1)*64 + nt*16 + l15];
      #pragma unroll
      for(int r=0;r<4;r++){
        int row = m0 + (w>>1)*64 + mt*16 + quad*4 + r;
        int col = n0 + (w&1)*64 + nt*16 + l15;
        size_t oi = ((size_t)b*DIMC+row)*LSP+col;
        Out[oi] = acc[mt][nt][r]*rv + Res[oi];
      }
    }
}

// ---------------- Depthwise 3x3 conv + bias + SiLU, IN-PLACE on XBC ----------------
__global__ void conv_kernel(u16* __restrict__ XBC, const float* __restrict__ CW,
                            const float* __restrict__ CB){
  int ch = blockIdx.x, b = blockIdx.y, tid = threadIdx.x;
  __shared__ float plane[66*66];
  u16* base = XBC + ((size_t)b*CONVDIM + ch)*LSP;
  for (int idx=tid; idx<66*66; idx+=256){
    int yy = idx/66 - 1, xx = idx%66 - 1;
    float v = 0.f;
    if (yy>=0 && yy<64 && xx>=0 && xx<64) v = bf2f(base[yy*64+xx]);
    plane[idx] = v;
  }
  float wg[9];
  #pragma unroll
  for (int t=0;t<9;t++) wg[t] = CW[ch*9+t];
  float bias = CB[ch];
  __syncthreads();
  for (int r=0;r<16;r++){
    int pix = tid + r*256;
    int y = pix>>6, x = pix&63;
    float s=0.f;
    #pragma unroll
    for(int dy=0;dy<3;dy++)
      #pragma unroll
      for(int dx=0;dx<3;dx++) s += plane[(y+dy)*66 + x+dx]*wg[dy*3+dx];
    base[pix] = f2bf(siluf(s + bias));
  }
}

// ---------------- SSD pre: dt softplus + per-chunk cumsum (LOG2E-scaled), ONCE ------
__global__ void ssd_pre_kernel(const u16* __restrict__ DT, const float* __restrict__ A_log,
                               const float* __restrict__ dt_bias, float* __restrict__ ACS,
                               float* __restrict__ DTV, float* __restrict__ DASUM){
  int c=blockIdx.x, h=blockIdx.y, b=blockIdx.z, tid=threadIdx.x;
  __shared__ float acs[CHUNK];
  size_t base = ((size_t)b*NHEADS+h)*LSP + c*CHUNK + tid;
  float raw = bf2f(DT[base]);
  float dtv = softplusf(raw + dt_bias[h]);
  float Ah = -__expf(A_log[h]);
  acs[tid] = dtv*Ah*LOG2E;   // pre-scaled: downstream uses exp2
  __syncthreads();
  for(int o=1;o<256;o<<=1){
    float add=(tid>=o)?acs[tid-o]:0.f;
    __syncthreads(); acs[tid]+=add; __syncthreads();
  }
  ACS[base] = acs[tid];
  DTV[base] = dtv;
  if (tid==CHUNK-1) DASUM[((size_t)b*NHEADS+h)*NCHUNK+c] = acs[tid];
}

// ---------------- SSD states (MFMA): states_T[p][n] = sum_t Xdtw[t][p]*B[t][n] ------
__global__ __launch_bounds__(256,4) void ssd_states_mfma(
    const float* __restrict__ ACS, const float* __restrict__ DTV,
    const float* __restrict__ DASUM, const u16* __restrict__ XBC,
    float* __restrict__ STATES){
  int c=blockIdx.x, h=blockIdx.y, b=blockIdx.z;
  int tid=threadIdx.x, w=tid>>6, lane=tid&63, l15=lane&15, quad=lane>>4;
  __shared__ float wdt[CHUNK];
  __shared__ u16 Xw[64][136];
  __shared__ u16 Bn[64][136];
  {
    size_t base = ((size_t)b*NHEADS+h)*LSP + c*CHUNK + tid;
    float atot = DASUM[((size_t)b*NHEADS+h)*NCHUNK+c];
    wdt[tid] = DTV[base]*exp2g(atot - ACS[base]);
  }
  __syncthreads();
  f32x4 acc[4];
  #pragma unroll
  for(int i=0;i<4;i++) acc[i] = (f32x4){0.f,0.f,0.f,0.f};
  size_t cb = (size_t)c*CHUNK;
  for(int th=0; th<2; th++){
    __syncthreads();
    {
      int n=tid&63, q4=tid>>6;
      const u16* Xg = XBC + ((size_t)b*CONVDIM + h*HEADDIM + n)*LSP + cb + th*128;
      const u16* Bg = XBC + ((size_t)b*CONVDIM + DINNER + n)*LSP + cb + th*128;
      #pragma unroll
      for(int i=0;i<4;i++){
        int o = q4*32+i*8;
        u16x8 v = *(const u16x8*)&Xg[o];
        u16x8 wv;
        #pragma unroll
        for(int j=0;j<8;j++) wv[j]=f2bf(bf2f(v[j])*wdt[th*128+o+j]);
        *(u16x8*)&Xw[n][o]=wv;
        *(u16x8*)&Bn[n][o] = *(const u16x8*)&Bg[o];
      }
    }
    __syncthreads();
    #pragma unroll
    for(int k8=0;k8<4;k8++){
      u16x8 a = *(const u16x8*)&Xw[w*16+l15][k8*32+quad*8];
      #pragma unroll
      for(int nt=0;nt<4;nt++){
        u16x8 bb = *(const u16x8*)&Bn[nt*16+l15][k8*32+quad*8];
        acc[nt]=MFMA16(a,bb,acc[nt]);
      }
    }
  }
  float* dst = STATES + (((size_t)b*NHEADS+h)*NCHUNK+c)*4096;
  #pragma unroll
  for(int nt=0;nt<4;nt++)
    #pragma unroll
    for(int r=0;r<4;r++)
      dst[(w*16+quad*4+r)*64 + nt*16+l15] = acc[nt][r];
}

// ---------------- inter-chunk scan -> PREVB bf16 [p][n] per (b,h,c) ----------------
__global__ void ssd_scan_kernel(const float* __restrict__ STATES, const float* __restrict__ DASUM,
                                u16* __restrict__ PREVB){
  int g = blockIdx.x, h = blockIdx.y, b = blockIdx.z, tid = threadIdx.x;
  int e = g*256 + tid;
  size_t hb = (size_t)b*NHEADS + h;
  size_t base = hb*NCHUNK*4096 + e;
  float s = 0.f;
  for (int cc=0;cc<NCHUNK;cc++){
    PREVB[base + (size_t)cc*4096] = f2bf(s);
    s = s*exp2g(DASUM[hb*NCHUNK + cc]) + STATES[base + (size_t)cc*4096];
  }
}

// ---------------- SSD Y (MFMA, band per block, 2 HEADS per block, v4) --------------
// v1's proven structure (X staged in LDS, 2 barriers/sb) + v3's harmless wins
// (exp2 pre-scale, Yo folded into Yd init) + SINGLE Ps buffer (heads sequential,
// wave-local rows) -> LDS 50176 -> 40960 B = exactly 4 blocks/CU (was 3).
__global__ __launch_bounds__(256,4) void ssd_y_mfma(
    const float* __restrict__ ACS, const float* __restrict__ DTV,
    const u16* __restrict__ XBC, const float* __restrict__ Dp,
    const u16* __restrict__ PREVB, const u16* __restrict__ ZT,
    u16* __restrict__ YG){
  int hp = blockIdx.x, bx = blockIdx.y, b = blockIdx.z;
  int h0 = hp*2;
  int c = bx>>2, tb = 3-(bx&3);
  int tid=threadIdx.x, w=tid>>6, lane=tid&63, l15=lane&15, quad=lane>>4;
  // carve: [0,2048) acs2; [2048,4096) dtv2; [4096,13312) Bs; [13312,31744) Xs[2]; [31744,40960) Ps
  __shared__ __align__(16) char smem[40960];
  float* acs2 = (float*)smem;           // [hh*256 + s]
  float* dtv2 = (float*)(smem+2048);
  typedef u16 u16row72[72];
  u16row72* Bs  = (u16row72*)(smem+4096);
  u16row72* Xs0 = (u16row72*)(smem+13312);
  u16row72* Xs1 = (u16row72*)(smem+22528);
  u16row72* Ps  = (u16row72*)(smem+31744);
  {
    size_t base0 = ((size_t)b*NHEADS+h0)*LSP + c*CHUNK + tid;
    acs2[tid]     = ACS[base0];
    dtv2[tid]     = DTV[base0];
    acs2[256+tid] = ACS[base0+LSP];
    dtv2[256+tid] = DTV[base0+LSP];
  }
  // C fragment: once-per-block strided gather, shared by both heads
  u16x8 ca0, ca1;
  {
    const u16* Cbase = XBC + ((size_t)b*CONVDIM + DINNER + DSTATE)*LSP
                     + (size_t)c*CHUNK + tb*64 + w*16 + l15;
    #pragma unroll
    for(int j=0;j<8;j++){
      ca0[j] = Cbase[(size_t)(quad*8+j)*LSP];
      ca1[j] = Cbase[(size_t)(32+quad*8+j)*LSP];
    }
  }
  __syncthreads();
  int tloc = tb*64 + w*16 + quad*4;
  float acst[2][4], eat2[2][4];
  #pragma unroll
  for(int hh=0;hh<2;hh++)
    #pragma unroll
    for(int r=0;r<4;r++){
      acst[hh][r] = acs2[hh*256 + tloc + r];
      eat2[hh][r] = exp2g(acst[hh][r]);
    }
  float DhA[2] = { Dp[h0], Dp[h0+1] };
  // Yd init = eat * (C . prev)  (folds Y_off scaling into the accumulator)
  f32x4 Yd[2][4];
  #pragma unroll
  for(int hh=0;hh<2;hh++){
    const u16* Pg = PREVB + (((size_t)b*NHEADS+h0+hh)*NCHUNK + c)*4096;
    #pragma unroll
    for(int pt=0;pt<4;pt++){
      f32x4 yo = (f32x4){0.f,0.f,0.f,0.f};
      u16x8 b0 = *(const u16x8*)&Pg[(pt*16+l15)*64 + quad*8];
      u16x8 b1 = *(const u16x8*)&Pg[(pt*16+l15)*64 + 32 + quad*8];
      yo = MFMA16(ca0,b0,yo);
      yo = MFMA16(ca1,b1,yo);
      #pragma unroll
      for(int r=0;r<4;r++) Yd[hh][pt][r] = eat2[hh][r]*yo[r];
    }
  }
  for(int sb=0; sb<=tb; sb++){
    __syncthreads();   // prev-iter reads of Bs/Xs done before overwrite
    {
      int n=tid&63, q4=tid>>6;
      const u16* Bg = XBC + ((size_t)b*CONVDIM + DINNER + n)*LSP + (size_t)c*CHUNK + sb*64;
      #pragma unroll
      for(int i=0;i<2;i++){
        u16x8 v = *(const u16x8*)&Bg[q4*16+i*8];
        #pragma unroll
        for(int j=0;j<8;j++) Bs[q4*16+i*8+j][n]=v[j];
      }
      #pragma unroll
      for(int hh=0;hh<2;hh++){
        u16row72* Xsh = hh ? Xs1 : Xs0;
        const u16* Xg = XBC + ((size_t)b*CONVDIM + (h0+hh)*HEADDIM + n)*LSP + (size_t)c*CHUNK + sb*64;
        #pragma unroll
        for(int i=0;i<2;i++){
          int o = q4*16+i*8;
          *(u16x8*)&Xsh[n][o] = *(const u16x8*)&Xg[o];
        }
      }
    }
    __syncthreads();
    // S = C.B^T (head-independent, computed once)
    f32x4 S[4];
    #pragma unroll
    for(int st=0;st<4;st++){
      S[st]=(f32x4){0.f,0.f,0.f,0.f};
      u16x8 b0 = *(const u16x8*)&Bs[st*16+l15][quad*8];
      u16x8 b1 = *(const u16x8*)&Bs[st*16+l15][32+quad*8];
      S[st]=MFMA16(ca0,b0,S[st]);
      S[st]=MFMA16(ca1,b1,S[st]);
    }
    // per-head: decay/dt transform -> Ps (single buffer, wave-local rows) -> Yd MFMAs
    #pragma unroll
    for(int hh=0;hh<2;hh++){
      u16row72* Xsh = hh ? Xs1 : Xs0;
      float Dh = DhA[hh];
      const float* acsh = acs2 + hh*256;
      const float* dtvh = dtv2 + hh*256;
      if (sb < tb){
        #pragma unroll
        for(int st=0;st<4;st++){
          int s = sb*64 + st*16 + l15;
          float as = acsh[s], dv = dtvh[s];
          #pragma unroll
          for(int r=0;r<4;r++)
            Ps[w*16+quad*4+r][st*16+l15] = f2bf(S[st][r]*exp2g(acst[hh][r]-as)*dv);
        }
      } else {
        #pragma unroll
        for(int st=0;st<4;st++){
          int s = sb*64 + st*16 + l15;
          float as = acsh[s], dv = dtvh[s];
          #pragma unroll
          for(int r=0;r<4;r++){
            int t = tloc + r;
            float pv;
            if (s < t)       pv = S[st][r]*exp2g(acst[hh][r]-as)*dv;
            else if (s == t) pv = S[st][r]*dv + Dh;
            else             pv = 0.f;
            Ps[w*16+quad*4+r][st*16+l15] = f2bf(pv);
          }
        }
      }
      u16x8 p0 = *(const u16x8*)&Ps[w*16+l15][quad*8];
      u16x8 p1 = *(const u16x8*)&Ps[w*16+l15][32+quad*8];
      #pragma unroll
      for(int pt=0;pt<4;pt++){
        u16x8 x0 = *(const u16x8*)&Xsh[pt*16+l15][quad*8];
        u16x8 x1 = *(const u16x8*)&Xsh[pt*16+l15][32+quad*8];
        Yd[hh][pt]=MFMA16(p0,x0,Yd[hh][pt]);
        Yd[hh][pt]=MFMA16(p1,x1,Yd[hh][pt]);
      }
    }
  }
  // epilogue: stage Y as f32 in smem (per head, sequential), coalesced ZT/YG pass
  __syncthreads();
  typedef float f32row66[66];
  f32row66* Yf = (f32row66*)smem;   // 64*66*4 = 16896 B <= 40960
  #pragma unroll
  for(int hh=0;hh<2;hh++){
    #pragma unroll
    for(int pt=0;pt<4;pt++)
      #pragma unroll
      for(int r=0;r<4;r++)
        Yf[w*16+quad*4+r][pt*16+l15] = Yd[hh][pt][r];
    __syncthreads();
    {
      int row = tid>>2, seg = tid&3;
      size_t lrow = (size_t)b*LSP + (size_t)c*CHUNK + tb*64 + row;
      size_t oi = lrow*DINNER + (size_t)(h0+hh)*HEADDIM + seg*16;
      u16x8 z0 = *(const u16x8*)&ZT[oi];
      u16x8 z1 = *(const u16x8*)&ZT[oi+8];
      u16x8 o0, o1;
      #pragma unroll
      for(int j=0;j<8;j++){
        o0[j] = f2bf(Yf[row][seg*16+j]   * siluf(bf2f(z0[j])));
        o1[j] = f2bf(Yf[row][seg*16+8+j] * siluf(bf2f(z1[j])));
      }
      *(u16x8*)&YG[oi]   = o0;
      *(u16x8*)&YG[oi+8] = o1;
    }
    if (hh==0) __syncthreads();
  }
}

extern "C" void kernel_launch(void* const* d_in, const int* in_sizes, int n_in,
                              void* d_out, int out_size, void* d_ws, size_t ws_size,
                              hipStream_t stream) {
  const float* x     = (const float*)d_in[0];
  const float* lnw   = (const float*)d_in[1];
  const float* lnb   = (const float*)d_in[2];
  const float* inpw  = (const float*)d_in[3];
  const float* convw = (const float*)d_in[4];
  const float* convb = (const float*)d_in[5];
  const float* alog  = (const float*)d_in[6];
  const float* Dp    = (const float*)d_in[7];
  const float* dtbi  = (const float*)d_in[8];
  const float* rmsw  = (const float*)d_in[9];
  const float* outw  = (const float*)d_in[10];
  float* out = (float*)d_out;

  char* ws = (char*)d_ws;
  size_t off = 0;
  auto alloc = [&](size_t bytes)->void*{ void* p = ws+off; off += (bytes+255)&~(size_t)255; return p; };
  u16*   WPIN   = (u16*)  alloc((size_t)MPAD*DIMC*2);
  u16*   WPOUT  = (u16*)  alloc((size_t)DIMC*DINNER*2);
  char*  RA     = (char*) alloc((size_t)BATCH*NHEADS*NCHUNK*4096*4);
  u16*   XNT    = (u16*)RA;
  float* STATES = (float*)RA;
  u16*   ZT     = (u16*)  alloc((size_t)BATCH*LSP*DINNER*2);
  u16*   XBC    = (u16*)  alloc((size_t)BATCH*CONVDIM*LSP*2);
  u16*   DTb    = (u16*)  alloc((size_t)BATCH*NHEADS*LSP*2);
  u16*   PREVB  = (u16*)  alloc((size_t)BATCH*NHEADS*NCHUNK*4096*2);
  float* DASUM  = (float*)alloc((size_t)BATCH*NHEADS*NCHUNK*4);
  float* ACS    = (float*)alloc((size_t)BATCH*NHEADS*LSP*4);
  float* DTV    = (float*)alloc((size_t)BATCH*NHEADS*LSP*4);
  u16*   YG     = (u16*)  alloc((size_t)BATCH*LSP*DINNER*2);

  convert_w<<<(MPAD*DIMC+255)/256,256,0,stream>>>(inpw, WPIN, MPAD*DIMC, DPROJ*DIMC);
  convert_w_rms<<<(DIMC*DINNER+255)/256,256,0,stream>>>(outw, rmsw, WPOUT);
  ln_kernel<<<dim3(BATCH*LSP/256),256,0,stream>>>(x,lnw,lnb,XNT);
  gemm_in_fused<<<dim3(LSP/128,2,BATCH),256,0,stream>>>(WPIN, XNT, ZT, XBC, DTb);
  conv_kernel<<<dim3(CONVDIM,BATCH),256,0,stream>>>(XBC, convw, convb);
  ssd_pre_kernel<<<dim3(NCHUNK,NHEADS,BATCH),256,0,stream>>>(DTb, alog, dtbi, ACS, DTV, DASUM);
  ssd_states_mfma<<<dim3(NCHUNK,NHEADS,BATCH),256,0,stream>>>(ACS,DTV,DASUM,XBC,STATES);
  ssd_scan_kernel<<<dim3(16,NHEADS,BATCH),256,0,stream>>>(STATES,DASUM,PREVB);
  ssd_y_mfma<<<dim3(NHEADS/2,NCHUNK*4,BATCH),256,0,stream>>>(ACS,DTV,XBC,Dp,PREVB,ZT,YG);
  gemm_out_mfma<<<dim3(LSP/128,DIMC/128,BATCH),256,0,stream>>>(WPOUT, YG, x, out);
}